// Round 7
// baseline (1503.737 us; speedup 1.0000x reference)
//
#include <hip/hip_runtime.h>
#include <cstdint>
#include <cstddef>

#define NN 262144
#define EE 2097152
#define BB 64
#define CCROSS 32
#define PCC 128
#define PP 2048
#define NBUCK 256
#define BCAP 12288

typedef _Float16 f16;
typedef __attribute__((ext_vector_type(4))) _Float16 f16x4;
typedef __attribute__((ext_vector_type(8))) _Float16 f16x8;

static __device__ __forceinline__ float lrelu(float x, float s) { return x > 0.f ? x : s * x; }

// ---------------- bucketed CSR build ----------------
__global__ __launch_bounds__(256) void bucket_a_k(const int* __restrict__ src, const int* __restrict__ dst,
                                                  unsigned* __restrict__ buckets, int* __restrict__ gcnt) {
    __shared__ int hist[NBUCK];
    __shared__ int base[NBUCK];
    __shared__ unsigned short rankbuf[8192];
    const int tid = threadIdx.x;
    const int e0 = blockIdx.x * 8192;
    hist[tid] = 0;
    __syncthreads();
    for (int i = tid; i < 8192; i += 256) {
        int d = dst[e0 + i];
        rankbuf[i] = (unsigned short)atomicAdd(&hist[d >> 10], 1);
    }
    __syncthreads();
    base[tid] = tid * BCAP + atomicAdd(&gcnt[tid], hist[tid]);
    __syncthreads();
    for (int i = tid; i < 8192; i += 256) {
        int s = src[e0 + i];
        int d = dst[e0 + i];
        int b = d >> 10;
        buckets[base[b] + rankbuf[i]] = ((unsigned)s << 10) | (unsigned)(d & 1023);
    }
}

__global__ void bucket_scan_k(const int* __restrict__ gcnt, int* __restrict__ bbase, int* __restrict__ rp) {
    __shared__ int tmp[256];
    int tid = threadIdx.x;
    int v = gcnt[tid];
    tmp[tid] = v;
    __syncthreads();
    for (int off = 1; off < 256; off <<= 1) {
        int t = (tid >= off) ? tmp[tid - off] : 0;
        __syncthreads();
        tmp[tid] += t;
        __syncthreads();
    }
    bbase[tid] = tmp[tid] - v;
    if (tid == 0) rp[NN] = EE;
}

__global__ __launch_bounds__(256) void bucket_b_k(const unsigned* __restrict__ buckets, const int* __restrict__ gcnt,
                                                  const int* __restrict__ bbase, int* __restrict__ rp,
                                                  float* __restrict__ dinv, int* __restrict__ col) {
    __shared__ int cnt[1024];
    __shared__ int scan[1024];
    __shared__ int wsum[256];
    const int b = blockIdx.x;
    const int tid = threadIdx.x;
    int n = gcnt[b];
    if (n > BCAP) n = BCAP;
    const unsigned* eb = buckets + (size_t)b * BCAP;
    const int gb = bbase[b];
    for (int i = tid; i < 1024; i += 256) cnt[i] = 0;
    __syncthreads();
    for (int i = tid; i < n; i += 256) atomicAdd(&cnt[eb[i] & 1023], 1);
    __syncthreads();
    int b4 = tid * 4;
    int c0 = cnt[b4], c1 = cnt[b4 + 1], c2 = cnt[b4 + 2], c3 = cnt[b4 + 3];
    int tsum = c0 + c1 + c2 + c3;
    wsum[tid] = tsum;
    __syncthreads();
    for (int off = 1; off < 256; off <<= 1) {
        int t = (tid >= off) ? wsum[tid - off] : 0;
        __syncthreads();
        wsum[tid] += t;
        __syncthreads();
    }
    int excl = wsum[tid] - tsum;
    scan[b4] = excl;
    scan[b4 + 1] = excl + c0;
    scan[b4 + 2] = excl + c0 + c1;
    scan[b4 + 3] = excl + c0 + c1 + c2;
    int vbase = b * 1024 + b4;
    rp[vbase + 0] = gb + scan[b4 + 0];
    rp[vbase + 1] = gb + scan[b4 + 1];
    rp[vbase + 2] = gb + scan[b4 + 2];
    rp[vbase + 3] = gb + scan[b4 + 3];
    dinv[vbase + 0] = rsqrtf((float)(c0 + 1));
    dinv[vbase + 1] = rsqrtf((float)(c1 + 1));
    dinv[vbase + 2] = rsqrtf((float)(c2 + 1));
    dinv[vbase + 3] = rsqrtf((float)(c3 + 1));
    __syncthreads();
    for (int i = tid; i < 1024; i += 256) cnt[i] = 0;
    __syncthreads();
    for (int i = tid; i < n; i += 256) {
        unsigned p = eb[i];
        int dl = p & 1023;
        int r = atomicAdd(&cnt[dl], 1);
        col[gb + scan[dl] + r] = (int)(p >> 10);
    }
}

// ---------------- z-prep: z[v] = dinv[v]*x[v] fp16, padded 19 -> 32 halfs (64B row, zero pad) ----------------
__global__ void zprep_k(const float* __restrict__ x, const float* __restrict__ dinv, f16* __restrict__ z) {
    int v = blockIdx.x * 256 + threadIdx.x;
    if (v >= NN) return;
    float dv = dinv[v];
    const float* xr = x + (size_t)v * 19;
    float vv[20];
#pragma unroll
    for (int k = 0; k < 19; k++) vv[k] = dv * xr[k];
    vv[19] = 0.f;
    f16x4* zr = (f16x4*)(z + (size_t)v * 32);
#pragma unroll
    for (int c = 0; c < 5; c++) {
        f16x4 t = {(f16)vv[4 * c], (f16)vv[4 * c + 1], (f16)vv[4 * c + 2], (f16)vv[4 * c + 3]};
        zr[c] = t;
    }
    f16x4 zz = {(f16)0.f, (f16)0.f, (f16)0.f, (f16)0.f};
#pragma unroll
    for (int c = 5; c < 8; c++) zr[c] = zz;
}

// ---------------- XCD-sliced aggregation over fp16 rows ----------------
// Row = SCH f16x4 chunks (SCH*8 bytes). NSL slices of 16B (one f16x8) each; HPR = SCH/2 f16x8 per row.
// blockIdx % NSL = slice -> round-robin XCD dispatch keeps each slice's array portion in one XCD's L2.
// GAT=false: out[v] = self + sum_nb. GAT=true: out[v] = (wself*self + sum w*nb)*invden + bias.
template <int SCH, int NSL, bool GAT>
__global__ __launch_bounds__(256) void agg_sliced_k(const f16* __restrict__ y, const int* __restrict__ rp,
                                                    const int* __restrict__ col, const f16* __restrict__ ew,
                                                    const float* __restrict__ wself, const float* __restrict__ invden,
                                                    const float* __restrict__ bias, float* __restrict__ out) {
    constexpr int HPR = SCH / 2;
    const int bid = blockIdx.x;
    const int s = bid % NSL;
    const int v = (bid / NSL) * 256 + threadIdx.x;
    const f16x8* y8 = (const f16x8*)y;
    f16x8 self = y8[(size_t)v * HPR + s];
    float acc[8];
    if constexpr (GAT) {
        float ws = wself[v];
#pragma unroll
        for (int j = 0; j < 8; j++) acc[j] = ws * (float)self[j];
    } else {
#pragma unroll
        for (int j = 0; j < 8; j++) acc[j] = (float)self[j];
    }
    int st = rp[v], e = rp[v + 1];
    int i = st;
    for (; i + 4 <= e; i += 4) {
        int u0 = col[i], u1 = col[i + 1], u2 = col[i + 2], u3 = col[i + 3];
        f16x8 r0 = y8[(size_t)u0 * HPR + s];
        f16x8 r1 = y8[(size_t)u1 * HPR + s];
        f16x8 r2 = y8[(size_t)u2 * HPR + s];
        f16x8 r3 = y8[(size_t)u3 * HPR + s];
        if constexpr (GAT) {
            float w0 = (float)ew[i], w1 = (float)ew[i + 1], w2 = (float)ew[i + 2], w3 = (float)ew[i + 3];
#pragma unroll
            for (int j = 0; j < 8; j++)
                acc[j] = fmaf(w0, (float)r0[j], fmaf(w1, (float)r1[j], fmaf(w2, (float)r2[j], fmaf(w3, (float)r3[j], acc[j]))));
        } else {
#pragma unroll
            for (int j = 0; j < 8; j++)
                acc[j] += ((float)r0[j] + (float)r1[j]) + ((float)r2[j] + (float)r3[j]);
        }
    }
    for (; i < e; i++) {
        f16x8 r = y8[(size_t)col[i] * HPR + s];
        if constexpr (GAT) {
            float w = (float)ew[i];
#pragma unroll
            for (int j = 0; j < 8; j++) acc[j] = fmaf(w, (float)r[j], acc[j]);
        } else {
#pragma unroll
            for (int j = 0; j < 8; j++) acc[j] += (float)r[j];
        }
    }
    float4 o0, o1;
    if constexpr (GAT) {
        float inv = invden[v];
        const float4* b4 = (const float4*)(bias + s * 8);
        float4 bb0 = b4[0], bb1 = b4[1];
        o0.x = acc[0] * inv + bb0.x; o0.y = acc[1] * inv + bb0.y;
        o0.z = acc[2] * inv + bb0.z; o0.w = acc[3] * inv + bb0.w;
        o1.x = acc[4] * inv + bb1.x; o1.y = acc[5] * inv + bb1.y;
        o1.z = acc[6] * inv + bb1.z; o1.w = acc[7] * inv + bb1.w;
    } else {
        o0.x = acc[0]; o0.y = acc[1]; o0.z = acc[2]; o0.w = acc[3];
        o1.x = acc[4]; o1.y = acc[5]; o1.z = acc[6]; o1.w = acc[7];
    }
    float4* op = (float4*)(out + (size_t)v * (SCH * 4) + s * 8);
    op[0] = o0; op[1] = o1;
}

// ---------------- LDS-staged skinny GEMM ----------------
// out = act(dinv*(x@W) + b); OMODE: 0 = fp32 out, 1 = fp16 out scaled by dinv (z for next agg), 2 = fp16 out
template <int KIN, int KSTR, int KOUT, int ACT, int OMODE>
__global__ __launch_bounds__(256) void gemm_lds_k(const float* __restrict__ x, const float* __restrict__ Wg,
                                                  const float* __restrict__ dinv, const float* __restrict__ bias,
                                                  float* __restrict__ yf, f16* __restrict__ yh) {
    constexpr int TPR = KOUT / 16;
    constexpr int RPB = 256 / TPR;
    __shared__ float Wl[KSTR * KOUT];
    const int tid = threadIdx.x;
    for (int i = tid; i < KSTR * KOUT; i += 256)
        Wl[i] = (i < KIN * KOUT) ? Wg[i] : 0.f;
    __syncthreads();
    const int row = blockIdx.x * RPB + (tid / TPR);
    const int t = tid % TPR;
    const float4* xr4 = (const float4*)(x + (size_t)row * KSTR);
    float4 a0 = {0.f, 0.f, 0.f, 0.f}, a1 = a0, a2 = a0, a3 = a0;
#pragma unroll 2
    for (int k4 = 0; k4 < KSTR / 4; k4++) {
        float4 xv = xr4[k4];
        const float* wb = Wl + (4 * k4) * KOUT + 16 * t;
#pragma unroll
        for (int kk = 0; kk < 4; kk++) {
            float xs = (kk == 0) ? xv.x : (kk == 1) ? xv.y : (kk == 2) ? xv.z : xv.w;
            const float4* wr = (const float4*)(wb + kk * KOUT);
            float4 w0 = wr[0], w1 = wr[1], w2 = wr[2], w3 = wr[3];
            a0.x = fmaf(xs, w0.x, a0.x); a0.y = fmaf(xs, w0.y, a0.y); a0.z = fmaf(xs, w0.z, a0.z); a0.w = fmaf(xs, w0.w, a0.w);
            a1.x = fmaf(xs, w1.x, a1.x); a1.y = fmaf(xs, w1.y, a1.y); a1.z = fmaf(xs, w1.z, a1.z); a1.w = fmaf(xs, w1.w, a1.w);
            a2.x = fmaf(xs, w2.x, a2.x); a2.y = fmaf(xs, w2.y, a2.y); a2.z = fmaf(xs, w2.z, a2.z); a2.w = fmaf(xs, w2.w, a2.w);
            a3.x = fmaf(xs, w3.x, a3.x); a3.y = fmaf(xs, w3.y, a3.y); a3.z = fmaf(xs, w3.z, a3.z); a3.w = fmaf(xs, w3.w, a3.w);
        }
    }
    float dv = dinv[row];
    const float4* bb = (const float4*)(bias + 16 * t);
    float4 b0 = bb[0], b1 = bb[1], b2 = bb[2], b3 = bb[3];
    a0.x = dv * a0.x + b0.x; a0.y = dv * a0.y + b0.y; a0.z = dv * a0.z + b0.z; a0.w = dv * a0.w + b0.w;
    a1.x = dv * a1.x + b1.x; a1.y = dv * a1.y + b1.y; a1.z = dv * a1.z + b1.z; a1.w = dv * a1.w + b1.w;
    a2.x = dv * a2.x + b2.x; a2.y = dv * a2.y + b2.y; a2.z = dv * a2.z + b2.z; a2.w = dv * a2.w + b2.w;
    a3.x = dv * a3.x + b3.x; a3.y = dv * a3.y + b3.y; a3.z = dv * a3.z + b3.z; a3.w = dv * a3.w + b3.w;
    if (ACT == 0) {
        a0.x = fmaxf(a0.x, 0.f); a0.y = fmaxf(a0.y, 0.f); a0.z = fmaxf(a0.z, 0.f); a0.w = fmaxf(a0.w, 0.f);
        a1.x = fmaxf(a1.x, 0.f); a1.y = fmaxf(a1.y, 0.f); a1.z = fmaxf(a1.z, 0.f); a1.w = fmaxf(a1.w, 0.f);
        a2.x = fmaxf(a2.x, 0.f); a2.y = fmaxf(a2.y, 0.f); a2.z = fmaxf(a2.z, 0.f); a2.w = fmaxf(a2.w, 0.f);
        a3.x = fmaxf(a3.x, 0.f); a3.y = fmaxf(a3.y, 0.f); a3.z = fmaxf(a3.z, 0.f); a3.w = fmaxf(a3.w, 0.f);
    } else {
        a0.x = lrelu(a0.x, 0.01f); a0.y = lrelu(a0.y, 0.01f); a0.z = lrelu(a0.z, 0.01f); a0.w = lrelu(a0.w, 0.01f);
        a1.x = lrelu(a1.x, 0.01f); a1.y = lrelu(a1.y, 0.01f); a1.z = lrelu(a1.z, 0.01f); a1.w = lrelu(a1.w, 0.01f);
        a2.x = lrelu(a2.x, 0.01f); a2.y = lrelu(a2.y, 0.01f); a2.z = lrelu(a2.z, 0.01f); a2.w = lrelu(a2.w, 0.01f);
        a3.x = lrelu(a3.x, 0.01f); a3.y = lrelu(a3.y, 0.01f); a3.z = lrelu(a3.z, 0.01f); a3.w = lrelu(a3.w, 0.01f);
    }
    if constexpr (OMODE == 0) {
        float4* yo = (float4*)(yf + (size_t)row * KOUT + 16 * t);
        yo[0] = a0; yo[1] = a1; yo[2] = a2; yo[3] = a3;
    } else {
        float s = (OMODE == 1) ? dv : 1.f;
        f16x8 h0 = {(f16)(a0.x * s), (f16)(a0.y * s), (f16)(a0.z * s), (f16)(a0.w * s),
                    (f16)(a1.x * s), (f16)(a1.y * s), (f16)(a1.z * s), (f16)(a1.w * s)};
        f16x8 h1 = {(f16)(a2.x * s), (f16)(a2.y * s), (f16)(a2.z * s), (f16)(a2.w * s),
                    (f16)(a3.x * s), (f16)(a3.y * s), (f16)(a3.z * s), (f16)(a3.w * s)};
        f16x8* yo = (f16x8*)(yh + (size_t)row * KOUT + 16 * t);
        yo[0] = h0; yo[1] = h1;
    }
}

// ---------------- LDS-staged GAT gemm (fp16 in, fp16 out, es/ed dots) ----------------
__global__ __launch_bounds__(256) void gat_gemm_lds_h_k(const f16* __restrict__ x, const float* __restrict__ Wg,
                                                        const float* __restrict__ av, const float* __restrict__ ad,
                                                        f16* __restrict__ y, float* __restrict__ es, float* __restrict__ ed) {
    __shared__ float Wl[64 * 64];
    const int tid = threadIdx.x;
    for (int i = tid; i < 4096; i += 256) Wl[i] = Wg[i];
    __syncthreads();
    const int row = blockIdx.x * 64 + (tid >> 2);
    const int t = tid & 3;
    const f16x4* xr = (const f16x4*)(x + (size_t)row * 64);
    float4 a0 = {0.f, 0.f, 0.f, 0.f}, a1 = a0, a2 = a0, a3 = a0;
#pragma unroll 2
    for (int k4 = 0; k4 < 16; k4++) {
        f16x4 xh = xr[k4];
        const float* wb = Wl + (4 * k4) * 64 + 16 * t;
#pragma unroll
        for (int kk = 0; kk < 4; kk++) {
            float xs = (kk == 0) ? (float)xh.x : (kk == 1) ? (float)xh.y : (kk == 2) ? (float)xh.z : (float)xh.w;
            const float4* wr = (const float4*)(wb + kk * 64);
            float4 w0 = wr[0], w1 = wr[1], w2 = wr[2], w3 = wr[3];
            a0.x = fmaf(xs, w0.x, a0.x); a0.y = fmaf(xs, w0.y, a0.y); a0.z = fmaf(xs, w0.z, a0.z); a0.w = fmaf(xs, w0.w, a0.w);
            a1.x = fmaf(xs, w1.x, a1.x); a1.y = fmaf(xs, w1.y, a1.y); a1.z = fmaf(xs, w1.z, a1.z); a1.w = fmaf(xs, w1.w, a1.w);
            a2.x = fmaf(xs, w2.x, a2.x); a2.y = fmaf(xs, w2.y, a2.y); a2.z = fmaf(xs, w2.z, a2.z); a2.w = fmaf(xs, w2.w, a2.w);
            a3.x = fmaf(xs, w3.x, a3.x); a3.y = fmaf(xs, w3.y, a3.y); a3.z = fmaf(xs, w3.z, a3.z); a3.w = fmaf(xs, w3.w, a3.w);
        }
    }
    const float4* av4 = (const float4*)(av + 16 * t);
    const float4* ad4 = (const float4*)(ad + 16 * t);
    float4 v0 = av4[0], v1 = av4[1], v2 = av4[2], v3 = av4[3];
    float4 d0 = ad4[0], d1 = ad4[1], d2 = ad4[2], d3 = ad4[3];
    float e1 = a0.x * v0.x + a0.y * v0.y + a0.z * v0.z + a0.w * v0.w
             + a1.x * v1.x + a1.y * v1.y + a1.z * v1.z + a1.w * v1.w
             + a2.x * v2.x + a2.y * v2.y + a2.z * v2.z + a2.w * v2.w
             + a3.x * v3.x + a3.y * v3.y + a3.z * v3.z + a3.w * v3.w;
    float e2 = a0.x * d0.x + a0.y * d0.y + a0.z * d0.z + a0.w * d0.w
             + a1.x * d1.x + a1.y * d1.y + a1.z * d1.z + a1.w * d1.w
             + a2.x * d2.x + a2.y * d2.y + a2.z * d2.z + a2.w * d2.w
             + a3.x * d3.x + a3.y * d3.y + a3.z * d3.z + a3.w * d3.w;
    e1 += __shfl_xor(e1, 1); e1 += __shfl_xor(e1, 2);
    e2 += __shfl_xor(e2, 1); e2 += __shfl_xor(e2, 2);
    if (t == 0) { es[row] = e1; ed[row] = e2; }
    f16x8 h0 = {(f16)a0.x, (f16)a0.y, (f16)a0.z, (f16)a0.w, (f16)a1.x, (f16)a1.y, (f16)a1.z, (f16)a1.w};
    f16x8 h1 = {(f16)a2.x, (f16)a2.y, (f16)a2.z, (f16)a2.w, (f16)a3.x, (f16)a3.y, (f16)a3.z, (f16)a3.w};
    f16x8* yo = (f16x8*)(y + (size_t)row * 64 + 16 * t);
    yo[0] = h0; yo[1] = h1;
}

// ---------------- GAT input gemm (fp32, small cross-graph path) ----------------
template <int KIN, int KOUT>
__global__ void gat_gemm_k(const float* __restrict__ x, const float* __restrict__ W,
                           float* __restrict__ y, const float* __restrict__ av, const float* __restrict__ ad,
                           float* __restrict__ es, float* __restrict__ ed, int n) {
    int v = blockIdx.x * 256 + threadIdx.x;
    if (v >= n) return;
    const float* xr = x + (size_t)v * KIN;
    float acc[KOUT];
#pragma unroll
    for (int j = 0; j < KOUT; j++) acc[j] = 0.f;
#pragma unroll 2
    for (int k = 0; k < KIN; k++) {
        float xv = xr[k];
#pragma unroll
        for (int j = 0; j < KOUT; j++) acc[j] = fmaf(xv, W[k * KOUT + j], acc[j]);
    }
    float e1 = 0.f, e2 = 0.f;
    float4* y4 = (float4*)(y + (size_t)v * KOUT);
#pragma unroll
    for (int j4 = 0; j4 < KOUT / 4; j4++) {
        float4 t;
        t.x = acc[4 * j4 + 0]; t.y = acc[4 * j4 + 1]; t.z = acc[4 * j4 + 2]; t.w = acc[4 * j4 + 3];
        y4[j4] = t;
        e1 = fmaf(t.x, av[4 * j4 + 0], e1); e1 = fmaf(t.y, av[4 * j4 + 1], e1);
        e1 = fmaf(t.z, av[4 * j4 + 2], e1); e1 = fmaf(t.w, av[4 * j4 + 3], e1);
        e2 = fmaf(t.x, ad[4 * j4 + 0], e2); e2 = fmaf(t.y, ad[4 * j4 + 1], e2);
        e2 = fmaf(t.z, ad[4 * j4 + 2], e2); e2 = fmaf(t.w, ad[4 * j4 + 3], e2);
    }
    es[v] = e1; ed[v] = e2;
}

// ---------------- GAT edge softmax weights (fp16 ew) ----------------
__global__ void gat_w_k(const float* __restrict__ es, const float* __restrict__ ed,
                        const int* __restrict__ rp, const int* __restrict__ col,
                        f16* __restrict__ ew, float* __restrict__ wself, float* __restrict__ invden) {
    int v = blockIdx.x * 256 + threadIdx.x;
    if (v >= NN) return;
    float edv = ed[v];
    float eself = lrelu(es[v] + edv, 0.2f);
    float m = eself;
    int s = rp[v], e = rp[v + 1];
    int i = s;
    float lg[32];
    int cntn = e - s;
    for (; i + 4 <= e; i += 4) {
        int u0 = col[i], u1 = col[i + 1], u2 = col[i + 2], u3 = col[i + 3];
        float t0 = lrelu(es[u0] + edv, 0.2f);
        float t1 = lrelu(es[u1] + edv, 0.2f);
        float t2 = lrelu(es[u2] + edv, 0.2f);
        float t3 = lrelu(es[u3] + edv, 0.2f);
        int k = i - s;
        if (k + 3 < 32) { lg[k] = t0; lg[k + 1] = t1; lg[k + 2] = t2; lg[k + 3] = t3; }
        m = fmaxf(m, fmaxf(fmaxf(t0, t1), fmaxf(t2, t3)));
    }
    for (; i < e; i++) {
        float t = lrelu(es[col[i]] + edv, 0.2f);
        int k = i - s;
        if (k < 32) lg[k] = t;
        m = fmaxf(m, t);
    }
    float wsl = __expf(eself - m);
    float den = wsl;
    for (i = s; i < e; i++) {
        int k = i - s;
        float t = (k < 32) ? lg[k] : lrelu(es[col[i]] + edv, 0.2f);
        float w = __expf(t - m);
        ew[i] = (f16)w;
        den += w;
    }
    (void)cntn;
    wself[v] = wsl;
    invden[v] = 1.f / den;
}

// ---------------- pooling ----------------
__global__ void pool_pieces_k(const float* __restrict__ in, float* __restrict__ out) {
    int gid = blockIdx.x * 256 + threadIdx.x;
    if (gid >= BB * CCROSS * 64) return;
    int f = gid & 63, g = gid >> 6;
    const float* p = in + (size_t)g * PCC * 64 + f;
    float s = 0.f;
#pragma unroll 8
    for (int i = 0; i < PCC; i++) s += p[(size_t)i * 64];
    out[gid] = s * (1.f / 128.f);
}

__global__ void pool_cross_k(const float* __restrict__ in, float* __restrict__ out) {
    int gid = blockIdx.x * 64 + threadIdx.x;
    if (gid >= BB * 64) return;
    int f = gid & 63, b = gid >> 6;
    const float* p = in + (size_t)b * CCROSS * 64 + f;
    float s = 0.f;
#pragma unroll
    for (int i = 0; i < CCROSS; i++) s += p[(size_t)i * 64];
    out[gid] = s * (1.f / 32.f);
}

// ---------------- dense cross-graph GAT ----------------
__global__ void cross_att_k(const float* __restrict__ xw, const float* __restrict__ es,
                            const float* __restrict__ ed, const float* __restrict__ bg,
                            float* __restrict__ out) {
    int gid = blockIdx.x * 256 + threadIdx.x;
    if (gid >= BB * CCROSS * 64) return;
    int f = gid & 63;
    int d = (gid >> 6) & 31;
    int g = gid >> 11;
    int base = g * CCROSS;
    float edd = ed[base + d];
    float m = -1e30f;
#pragma unroll
    for (int s = 0; s < CCROSS; s++) {
        float e = lrelu(es[base + s] + edd, 0.2f);
        m = fmaxf(m, e);
    }
    float den = 0.f, acc = 0.f;
#pragma unroll
    for (int s = 0; s < CCROSS; s++) {
        float e = lrelu(es[base + s] + edd, 0.2f);
        float w = __expf(e - m) * ((s == d) ? 1.f : 2.f);
        den += w;
        acc = fmaf(w, xw[(size_t)(base + s) * 64 + f], acc);
    }
    out[gid] = acc / den + bg[f];
}

// ---------------- fused conv branch ----------------
#define S0_STR 264
#define S1_STR 132
#define S2_STR 66
#define S0_OFF 0
#define S1_OFF (3 * S0_STR)
#define S2_OFF (S1_OFF + 32 * S1_STR)
#define SMEM_FLOATS (S2_OFF + 64 * S2_STR)

__global__ __launch_bounds__(256) void conv_fused_k(
        const float* __restrict__ pts, const float* __restrict__ c1W, const float* __restrict__ c1b,
        const float* __restrict__ g1, const float* __restrict__ be1,
        const float* __restrict__ c2W, const float* __restrict__ c2b,
        const float* __restrict__ g2, const float* __restrict__ be2,
        const float* __restrict__ c3W, const float* __restrict__ c3b,
        float* __restrict__ partials) {
    __shared__ float smem[SMEM_FLOATS];
    float* s0 = smem + S0_OFF;
    float* s1 = smem + S1_OFF;
    float* s2 = smem + S2_OFF;
    float* s3 = smem;

    const int b = blockIdx.x >> 3;
    const int q = blockIdx.x & 7;
    const int tid = threadIdx.x;
    const float bnscale = 0.99999500003749968f;

    const int lo0 = 256 * q - 7;
    for (int t = tid; t < 3 * 263; t += 256) {
        int c = t / 263, j = t - c * 263;
        int p = lo0 + j;
        s0[c * S0_STR + j] = (p >= 0 && p < PP) ? pts[((size_t)b * 3 + c) * PP + p] : 0.f;
    }
    __syncthreads();

    const int lo1 = 128 * q - 3;
    for (int t = tid; t < 32 * 131; t += 256) {
        int ch = t / 131, j = t - ch * 131;
        int p1 = lo1 + j;
        float v = 0.f;
        if (p1 >= 0 && p1 < 1024) {
            float acc = c1b[ch];
            const float* w = c1W + ch * 9;
            const float* x0 = s0 + 2 * j;
#pragma unroll
            for (int ci = 0; ci < 3; ci++) {
                acc = fmaf(x0[ci * S0_STR + 0], w[ci * 3 + 0], acc);
                acc = fmaf(x0[ci * S0_STR + 1], w[ci * 3 + 1], acc);
                acc = fmaf(x0[ci * S0_STR + 2], w[ci * 3 + 2], acc);
            }
            acc = lrelu(acc, 0.01f);
            v = fmaf(acc, g1[ch] * bnscale, be1[ch]);
        }
        s1[ch * S1_STR + j] = v;
    }
    __syncthreads();

    const int lo2 = 64 * q - 1;
    for (int t = tid; t < 64 * 65; t += 256) {
        int ch = t / 65, j = t - ch * 65;
        int p2 = lo2 + j;
        float v = 0.f;
        if (p2 >= 0 && p2 < 512) {
            float acc = c2b[ch];
            const float* w = c2W + ch * 96;
            const float* x1 = s1 + 2 * j;
#pragma unroll
            for (int ci = 0; ci < 32; ci++) {
                acc = fmaf(x1[ci * S1_STR + 0], w[ci * 3 + 0], acc);
                acc = fmaf(x1[ci * S1_STR + 1], w[ci * 3 + 1], acc);
                acc = fmaf(x1[ci * S1_STR + 2], w[ci * 3 + 2], acc);
            }
            acc = lrelu(acc, 0.01f);
            v = fmaf(acc, g2[ch] * bnscale, be2[ch]);
        }
        s2[ch * S2_STR + j] = v;
    }
    __syncthreads();

    for (int t = tid; t < 64 * 32; t += 256) {
        int o = t >> 5, j = t & 31;
        float acc = c3b[o];
        const float* w = c3W + o * 192;
        const float* x2 = s2 + 2 * j;
#pragma unroll 16
        for (int ci = 0; ci < 64; ci++) {
            acc = fmaf(x2[ci * S2_STR + 0], w[ci * 3 + 0], acc);
            acc = fmaf(x2[ci * S2_STR + 1], w[ci * 3 + 1], acc);
            acc = fmaf(x2[ci * S2_STR + 2], w[ci * 3 + 2], acc);
        }
        s3[t] = lrelu(acc, 0.01f);
    }
    __syncthreads();

    if (tid < 64) {
        float s = 0.f;
#pragma unroll
        for (int j = 0; j < 32; j++) s += s3[tid * 32 + j];
        partials[((size_t)b * 8 + q) * 64 + tid] = s;
    }
}

// ---------------- head ----------------
__global__ void head_k(const float* __restrict__ hG, const float* __restrict__ partials,
                       const float* __restrict__ Wl2, const float* __restrict__ bl2,
                       const float* __restrict__ Wl3, const float* __restrict__ bl3,
                       float* __restrict__ out) {
    int b = blockIdx.x;
    int f = threadIdx.x;  // 64
    __shared__ float sh[64];
    float p = 0.f;
#pragma unroll
    for (int q = 0; q < 8; q++) p += partials[((size_t)b * 8 + q) * 64 + f];
    float h = hG[b * 64 + f] + p * (1.f / 256.f);
    sh[f] = h;
    __syncthreads();
    float acc = bl2[f];
#pragma unroll
    for (int k = 0; k < 64; k++) acc = fmaf(sh[k], Wl2[k * 64 + f], acc);
    acc = lrelu(acc, 0.01f);
    float pr = acc * Wl3[f];
#pragma unroll
    for (int off = 32; off > 0; off >>= 1) pr += __shfl_down(pr, off, 64);
    if (f == 0) out[b] = 1.f / (1.f + __expf(-(pr + bl3[0])));
}

extern "C" void kernel_launch(void* const* d_in, const int* in_sizes, int n_in,
                              void* d_out, int out_size, void* d_ws, size_t ws_size,
                              hipStream_t stream) {
    const float* x = (const float*)d_in[0];
    const int* ei = (const int*)d_in[1];
    const float* points = (const float*)d_in[2];
    const float* W1 = (const float*)d_in[3];
    const float* b1 = (const float*)d_in[4];
    const float* W2 = (const float*)d_in[5];
    const float* b2 = (const float*)d_in[6];
    const float* W3 = (const float*)d_in[7];
    const float* b3 = (const float*)d_in[8];
    const float* Wg1 = (const float*)d_in[9];
    const float* asrc1 = (const float*)d_in[10];
    const float* adst1 = (const float*)d_in[11];
    const float* bg1 = (const float*)d_in[12];
    const float* Wg2 = (const float*)d_in[13];
    const float* asrc2 = (const float*)d_in[14];
    const float* adst2 = (const float*)d_in[15];
    const float* bg2 = (const float*)d_in[16];
    const float* c1W = (const float*)d_in[17];
    const float* c1b = (const float*)d_in[18];
    const float* g1 = (const float*)d_in[19];
    const float* be1 = (const float*)d_in[20];
    const float* c2W = (const float*)d_in[21];
    const float* c2b = (const float*)d_in[22];
    const float* g2 = (const float*)d_in[23];
    const float* be2 = (const float*)d_in[24];
    const float* c3W = (const float*)d_in[25];
    const float* c3b = (const float*)d_in[26];
    const float* Wl2 = (const float*)d_in[27];
    const float* bl2 = (const float*)d_in[28];
    const float* Wl3 = (const float*)d_in[29];
    const float* bl3 = (const float*)d_in[30];

    const int* src = ei;
    const int* dst = ei + EE;

    // ---- workspace carve-up ----
    char* w = (char*)d_ws;
    size_t off = 0;
    auto A = [&](size_t bytes) -> void* {
        void* p = w + off;
        off = (off + bytes + 255) & ~(size_t)255;
        return p;
    };
    int* colb = (int*)A((size_t)EE * 4);
    int* rp = (int*)A((size_t)(NN + 1) * 4);
    int* gcnt = (int*)A(NBUCK * 4);
    int* bbase = (int*)A(NBUCK * 4);
    float* dinv = (float*)A((size_t)NN * 4);
    float* bufA = (float*)A((size_t)NN * 64 * 4);
    float* bufB = (float*)A((size_t)NN * 64 * 4);
    f16* bufH = (f16*)A((size_t)NN * 64 * 2);
    f16* ew = (f16*)A((size_t)EE * 2);
    float* wself = (float*)A((size_t)NN * 4);
    float* invden = (float*)A((size_t)NN * 4);
    float* es = (float*)A((size_t)NN * 4);
    float* edv = (float*)A((size_t)NN * 4);
    float* pooled = (float*)A((size_t)BB * CCROSS * 64 * 4);
    float* xw2 = (float*)A((size_t)BB * CCROSS * 64 * 4);
    float* es2 = (float*)A((size_t)BB * CCROSS * 4);
    float* ed2 = (float*)A((size_t)BB * CCROSS * 4);
    float* crosso = (float*)A((size_t)BB * CCROSS * 64 * 4);
    float* hG = (float*)A((size_t)BB * 64 * 4);
    float* partials = (float*)A((size_t)BB * 8 * 64 * 4);

    unsigned* buckets = (unsigned*)bufA;   // aliases bufA, dead before first real use
    f16* h3 = (f16*)bufB;                  // h3 fp16 lives in bufB region

    // ---- CSR build (bucketed) ----
    hipMemsetAsync(gcnt, 0, NBUCK * 4, stream);
    bucket_a_k<<<EE / 8192, 256, 0, stream>>>(src, dst, buckets, gcnt);
    bucket_scan_k<<<1, 256, 0, stream>>>(gcnt, bbase, rp);
    bucket_b_k<<<NBUCK, 256, 0, stream>>>(buckets, gcnt, bbase, rp, dinv, colb);

    // ---- points branch ----
    conv_fused_k<<<BB * 8, 256, 0, stream>>>(points, c1W, c1b, g1, be1, c2W, c2b, g2, be2, c3W, c3b, partials);

    // ---- GCN 1/2/3 (aggregate-before-transform, fp16 arrays, XCD-sliced gathers, LDS gemms) ----
    zprep_k<<<NN / 256, 256, 0, stream>>>(x, dinv, bufH);                                  // bufH = z1 [NN x 32h]
    agg_sliced_k<8, 4, false><<<(NN / 256) * 4, 256, 0, stream>>>(bufH, rp, colb, nullptr, nullptr, nullptr, nullptr, bufA);  // bufA = agg(z1) [NN x 32f]
    gemm_lds_k<19, 32, 32, 0, 1><<<NN / 128, 256, 0, stream>>>(bufA, W1, dinv, b1, nullptr, bufH);  // bufH = z2 [NN x 32h]
    agg_sliced_k<8, 4, false><<<(NN / 256) * 4, 256, 0, stream>>>(bufH, rp, colb, nullptr, nullptr, nullptr, nullptr, bufA);  // bufA = agg(z2) [NN x 32f]
    gemm_lds_k<32, 32, 64, 1, 1><<<NN / 64, 256, 0, stream>>>(bufA, W2, dinv, b2, nullptr, bufH);   // bufH = z3 [NN x 64h]
    agg_sliced_k<16, 8, false><<<(NN / 256) * 8, 256, 0, stream>>>(bufH, rp, colb, nullptr, nullptr, nullptr, nullptr, bufA); // bufA = agg(z3) [NN x 64f]
    gemm_lds_k<64, 64, 64, 1, 2><<<NN / 64, 256, 0, stream>>>(bufA, W3, dinv, b3, nullptr, h3);     // h3 (fp16)

    // ---- GAT 1 ----
    gat_gemm_lds_h_k<<<NN / 64, 256, 0, stream>>>(h3, Wg1, asrc1, adst1, bufH, es, edv);  // bufH = xw (fp16)
    gat_w_k<<<NN / 256, 256, 0, stream>>>(es, edv, rp, colb, ew, wself, invden);
    agg_sliced_k<16, 8, true><<<(NN / 256) * 8, 256, 0, stream>>>(bufH, rp, colb, ew, wself, invden, bg1, bufA);  // bufA = gat out

    // ---- pool pieces -> cross GAT -> pool cross ----
    pool_pieces_k<<<(BB * CCROSS * 64) / 256, 256, 0, stream>>>(bufA, pooled);
    gat_gemm_k<64, 64><<<(BB * CCROSS) / 256, 256, 0, stream>>>(pooled, Wg2, xw2, asrc2, adst2, es2, ed2, BB * CCROSS);
    cross_att_k<<<(BB * CCROSS * 64) / 256, 256, 0, stream>>>(xw2, es2, ed2, bg2, crosso);
    pool_cross_k<<<BB, 64, 0, stream>>>(crosso, hG);

    // ---- head ----
    head_k<<<BB, 64, 0, stream>>>(hG, partials, Wl2, bl2, Wl3, bl3, (float*)d_out);
}

// Round 8
// 637.605 us; speedup vs baseline: 2.3584x; 2.3584x over previous
//
#include <hip/hip_runtime.h>
#include <cstdint>
#include <cstddef>

#define NN 262144
#define EE 2097152
#define BB 64
#define CCROSS 32
#define PCC 128
#define PP 2048
#define NBUCK 256
#define BCAP 12288

typedef _Float16 f16;
typedef __attribute__((ext_vector_type(4))) _Float16 f16x4;
typedef __attribute__((ext_vector_type(8))) _Float16 f16x8;

static __device__ __forceinline__ float lrelu(float x, float s) { return x > 0.f ? x : s * x; }

// ---------------- bucketed CSR build ----------------
__global__ __launch_bounds__(256) void bucket_a_k(const int* __restrict__ src, const int* __restrict__ dst,
                                                  unsigned* __restrict__ buckets, int* __restrict__ gcnt) {
    __shared__ int hist[NBUCK];
    __shared__ int base[NBUCK];
    __shared__ unsigned short rankbuf[8192];
    const int tid = threadIdx.x;
    const int e0 = blockIdx.x * 8192;
    hist[tid] = 0;
    __syncthreads();
    for (int i = tid; i < 8192; i += 256) {
        int d = dst[e0 + i];
        rankbuf[i] = (unsigned short)atomicAdd(&hist[d >> 10], 1);
    }
    __syncthreads();
    base[tid] = tid * BCAP + atomicAdd(&gcnt[tid], hist[tid]);
    __syncthreads();
    for (int i = tid; i < 8192; i += 256) {
        int s = src[e0 + i];
        int d = dst[e0 + i];
        int b = d >> 10;
        buckets[base[b] + rankbuf[i]] = ((unsigned)s << 10) | (unsigned)(d & 1023);
    }
}

__global__ void bucket_scan_k(const int* __restrict__ gcnt, int* __restrict__ bbase, int* __restrict__ rp) {
    __shared__ int tmp[256];
    int tid = threadIdx.x;
    int v = gcnt[tid];
    tmp[tid] = v;
    __syncthreads();
    for (int off = 1; off < 256; off <<= 1) {
        int t = (tid >= off) ? tmp[tid - off] : 0;
        __syncthreads();
        tmp[tid] += t;
        __syncthreads();
    }
    bbase[tid] = tmp[tid] - v;
    if (tid == 0) rp[NN] = EE;
}

__global__ __launch_bounds__(256) void bucket_b_k(const unsigned* __restrict__ buckets, const int* __restrict__ gcnt,
                                                  const int* __restrict__ bbase, int* __restrict__ rp,
                                                  float* __restrict__ dinv, int* __restrict__ col) {
    __shared__ int cnt[1024];
    __shared__ int scan[1024];
    __shared__ int wsum[256];
    const int b = blockIdx.x;
    const int tid = threadIdx.x;
    int n = gcnt[b];
    if (n > BCAP) n = BCAP;
    const unsigned* eb = buckets + (size_t)b * BCAP;
    const int gb = bbase[b];
    for (int i = tid; i < 1024; i += 256) cnt[i] = 0;
    __syncthreads();
    for (int i = tid; i < n; i += 256) atomicAdd(&cnt[eb[i] & 1023], 1);
    __syncthreads();
    int b4 = tid * 4;
    int c0 = cnt[b4], c1 = cnt[b4 + 1], c2 = cnt[b4 + 2], c3 = cnt[b4 + 3];
    int tsum = c0 + c1 + c2 + c3;
    wsum[tid] = tsum;
    __syncthreads();
    for (int off = 1; off < 256; off <<= 1) {
        int t = (tid >= off) ? wsum[tid - off] : 0;
        __syncthreads();
        wsum[tid] += t;
        __syncthreads();
    }
    int excl = wsum[tid] - tsum;
    scan[b4] = excl;
    scan[b4 + 1] = excl + c0;
    scan[b4 + 2] = excl + c0 + c1;
    scan[b4 + 3] = excl + c0 + c1 + c2;
    int vbase = b * 1024 + b4;
    rp[vbase + 0] = gb + scan[b4 + 0];
    rp[vbase + 1] = gb + scan[b4 + 1];
    rp[vbase + 2] = gb + scan[b4 + 2];
    rp[vbase + 3] = gb + scan[b4 + 3];
    dinv[vbase + 0] = rsqrtf((float)(c0 + 1));
    dinv[vbase + 1] = rsqrtf((float)(c1 + 1));
    dinv[vbase + 2] = rsqrtf((float)(c2 + 1));
    dinv[vbase + 3] = rsqrtf((float)(c3 + 1));
    __syncthreads();
    for (int i = tid; i < 1024; i += 256) cnt[i] = 0;
    __syncthreads();
    for (int i = tid; i < n; i += 256) {
        unsigned p = eb[i];
        int dl = p & 1023;
        int r = atomicAdd(&cnt[dl], 1);
        col[gb + scan[dl] + r] = (int)(p >> 10);
    }
}

// ---------------- z-prep: z1[v] = dinv[v]*x[v] fp16, padded 19 -> 32 halfs ----------------
__global__ void zprep_k(const float* __restrict__ x, const float* __restrict__ dinv, f16* __restrict__ z) {
    int v = blockIdx.x * 256 + threadIdx.x;
    if (v >= NN) return;
    float dv = dinv[v];
    const float* xr = x + (size_t)v * 19;
    float vv[20];
#pragma unroll
    for (int k = 0; k < 19; k++) vv[k] = dv * xr[k];
    vv[19] = 0.f;
    f16x4* zr = (f16x4*)(z + (size_t)v * 32);
#pragma unroll
    for (int c = 0; c < 5; c++) {
        f16x4 t = {(f16)vv[4 * c], (f16)vv[4 * c + 1], (f16)vv[4 * c + 2], (f16)vv[4 * c + 3]};
        zr[c] = t;
    }
    f16x4 zz = {(f16)0.f, (f16)0.f, (f16)0.f, (f16)0.f};
#pragma unroll
    for (int c = 5; c < 8; c++) zr[c] = zz;
}

// ---------------- fused agg (64B fp16 rows) + gemm: zout = dinv * act(dinv*(agg(z)@W) + b) ----------------
// 32 rows/block; phase1: 8 lanes/row gather f16x4 chunks -> zrow LDS; phase2: 8 thr/row, KOUT/8 outs each.
template <int KINR, int KOUT, int ACT>
__global__ __launch_bounds__(256) void fused_agg_gemm_k(const f16* __restrict__ z, const int* __restrict__ rp,
                                                        const int* __restrict__ col, const float* __restrict__ Wg,
                                                        const float* __restrict__ dinv, const float* __restrict__ bias,
                                                        f16* __restrict__ zout) {
    constexpr int NO = KOUT / 8;
    __shared__ float Wl[32 * KOUT];
    __shared__ float zrow[32 * 32];
    const int tid = threadIdx.x;
    for (int i = tid; i < 32 * KOUT; i += 256) Wl[i] = (i < KINR * KOUT) ? Wg[i] : 0.f;

    const int r = tid >> 3;
    const int idx = tid & 7;
    const int v = blockIdx.x * 32 + r;
    const f16x4* z4 = (const f16x4*)z;
    f16x4 a = z4[(size_t)v * 8 + idx];
    float ax = (float)a.x, ay = (float)a.y, az = (float)a.z, aw = (float)a.w;
    int st = rp[v], e = rp[v + 1];
    int i = st;
    for (; i + 4 <= e; i += 4) {
        int u0 = col[i], u1 = col[i + 1], u2 = col[i + 2], u3 = col[i + 3];
        f16x4 a0 = z4[(size_t)u0 * 8 + idx];
        f16x4 a1 = z4[(size_t)u1 * 8 + idx];
        f16x4 a2 = z4[(size_t)u2 * 8 + idx];
        f16x4 a3 = z4[(size_t)u3 * 8 + idx];
        ax += ((float)a0.x + (float)a1.x) + ((float)a2.x + (float)a3.x);
        ay += ((float)a0.y + (float)a1.y) + ((float)a2.y + (float)a3.y);
        az += ((float)a0.z + (float)a1.z) + ((float)a2.z + (float)a3.z);
        aw += ((float)a0.w + (float)a1.w) + ((float)a2.w + (float)a3.w);
    }
    for (; i < e; i++) {
        f16x4 aa = z4[(size_t)col[i] * 8 + idx];
        ax += (float)aa.x; ay += (float)aa.y; az += (float)aa.z; aw += (float)aa.w;
    }
    float4 s; s.x = ax; s.y = ay; s.z = az; s.w = aw;
    *(float4*)&zrow[r * 32 + idx * 4] = s;
    __syncthreads();

    // phase 2: same thread mapping (8 threads/row), NO outs each
    float acc[NO];
#pragma unroll
    for (int j = 0; j < NO; j++) acc[j] = 0.f;
#pragma unroll 4
    for (int k = 0; k < 32; k++) {
        float zv = zrow[r * 32 + k];
        const float* wr = Wl + k * KOUT + NO * idx;
#pragma unroll
        for (int j = 0; j < NO; j++) acc[j] = fmaf(zv, wr[j], acc[j]);
    }
    float dv = dinv[v];
    f16 hv[NO];
#pragma unroll
    for (int j = 0; j < NO; j++) {
        float o = dv * acc[j] + bias[NO * idx + j];
        o = (ACT == 0) ? fmaxf(o, 0.f) : lrelu(o, 0.01f);
        hv[j] = (f16)(o * dv);
    }
    if constexpr (NO == 4) {
        f16x4 h = {hv[0], hv[1], hv[2], hv[3]};
        *(f16x4*)(zout + (size_t)v * KOUT + NO * idx) = h;
    } else {
        f16x8 h = {hv[0], hv[1], hv[2], hv[3], hv[4], hv[5], hv[6], hv[7]};
        *(f16x8*)(zout + (size_t)v * KOUT + NO * idx) = h;
    }
}

// ---------------- fused agg (128B rows) + gemm W3 + gat gemm Wg1 + es/ed dots ----------------
// 16 rows/block; 16 lanes/row.
__global__ __launch_bounds__(256) void fused_agg_gemm_gat_k(const f16* __restrict__ z, const int* __restrict__ rp,
                                                            const int* __restrict__ col, const float* __restrict__ W3,
                                                            const float* __restrict__ dinv, const float* __restrict__ b3,
                                                            const float* __restrict__ Wg1, const float* __restrict__ av,
                                                            const float* __restrict__ ad, f16* __restrict__ xw,
                                                            float* __restrict__ es, float* __restrict__ ed) {
    __shared__ float W3l[64 * 64];
    __shared__ float Wgl[64 * 64];
    __shared__ float zrow[16 * 64];
    __shared__ float hrow[16 * 64];
    const int tid = threadIdx.x;
    for (int i = tid; i < 4096; i += 256) { W3l[i] = W3[i]; Wgl[i] = Wg1[i]; }

    const int r = tid >> 4;
    const int idx = tid & 15;
    const int v = blockIdx.x * 16 + r;
    const f16x4* z4 = (const f16x4*)z;
    f16x4 a = z4[(size_t)v * 16 + idx];
    float ax = (float)a.x, ay = (float)a.y, az = (float)a.z, aw = (float)a.w;
    int st = rp[v], e = rp[v + 1];
    int i = st;
    for (; i + 4 <= e; i += 4) {
        int u0 = col[i], u1 = col[i + 1], u2 = col[i + 2], u3 = col[i + 3];
        f16x4 a0 = z4[(size_t)u0 * 16 + idx];
        f16x4 a1 = z4[(size_t)u1 * 16 + idx];
        f16x4 a2 = z4[(size_t)u2 * 16 + idx];
        f16x4 a3 = z4[(size_t)u3 * 16 + idx];
        ax += ((float)a0.x + (float)a1.x) + ((float)a2.x + (float)a3.x);
        ay += ((float)a0.y + (float)a1.y) + ((float)a2.y + (float)a3.y);
        az += ((float)a0.z + (float)a1.z) + ((float)a2.z + (float)a3.z);
        aw += ((float)a0.w + (float)a1.w) + ((float)a2.w + (float)a3.w);
    }
    for (; i < e; i++) {
        f16x4 aa = z4[(size_t)col[i] * 16 + idx];
        ax += (float)aa.x; ay += (float)aa.y; az += (float)aa.z; aw += (float)aa.w;
    }
    float4 s; s.x = ax; s.y = ay; s.z = az; s.w = aw;
    *(float4*)&zrow[r * 64 + idx * 4] = s;
    __syncthreads();

    // phase 2: gemm W3, 16 thr/row x 4 outs; epilogue -> hrow (h3)
    {
        float4 acc = {0.f, 0.f, 0.f, 0.f};
#pragma unroll 4
        for (int k = 0; k < 64; k++) {
            float zv = zrow[r * 64 + k];
            float4 wv = *(const float4*)&W3l[k * 64 + 4 * idx];
            acc.x = fmaf(zv, wv.x, acc.x); acc.y = fmaf(zv, wv.y, acc.y);
            acc.z = fmaf(zv, wv.z, acc.z); acc.w = fmaf(zv, wv.w, acc.w);
        }
        float dv = dinv[v];
        const float4 bb = *(const float4*)&b3[4 * idx];
        float4 o;
        o.x = lrelu(dv * acc.x + bb.x, 0.01f);
        o.y = lrelu(dv * acc.y + bb.y, 0.01f);
        o.z = lrelu(dv * acc.z + bb.z, 0.01f);
        o.w = lrelu(dv * acc.w + bb.w, 0.01f);
        *(float4*)&hrow[r * 64 + 4 * idx] = o;
    }
    __syncthreads();

    // phase 3: gat gemm Wg1 + dots
    {
        float4 g = {0.f, 0.f, 0.f, 0.f};
#pragma unroll 4
        for (int k = 0; k < 64; k++) {
            float hv = hrow[r * 64 + k];
            float4 wv = *(const float4*)&Wgl[k * 64 + 4 * idx];
            g.x = fmaf(hv, wv.x, g.x); g.y = fmaf(hv, wv.y, g.y);
            g.z = fmaf(hv, wv.z, g.z); g.w = fmaf(hv, wv.w, g.w);
        }
        const float4 v1 = *(const float4*)&av[4 * idx];
        const float4 d1 = *(const float4*)&ad[4 * idx];
        float e1 = g.x * v1.x + g.y * v1.y + g.z * v1.z + g.w * v1.w;
        float e2 = g.x * d1.x + g.y * d1.y + g.z * d1.z + g.w * d1.w;
        e1 += __shfl_xor(e1, 1); e1 += __shfl_xor(e1, 2);
        e1 += __shfl_xor(e1, 4); e1 += __shfl_xor(e1, 8);
        e2 += __shfl_xor(e2, 1); e2 += __shfl_xor(e2, 2);
        e2 += __shfl_xor(e2, 4); e2 += __shfl_xor(e2, 8);
        if (idx == 0) { es[v] = e1; ed[v] = e2; }
        f16x4 h = {(f16)g.x, (f16)g.y, (f16)g.z, (f16)g.w};
        *(f16x4*)(xw + (size_t)v * 64 + 4 * idx) = h;
    }
}

// ---------------- GAT edge softmax weights (fp16 ew) ----------------
__global__ void gat_w_k(const float* __restrict__ es, const float* __restrict__ ed,
                        const int* __restrict__ rp, const int* __restrict__ col,
                        f16* __restrict__ ew, float* __restrict__ wself, float* __restrict__ invden) {
    int v = blockIdx.x * 256 + threadIdx.x;
    if (v >= NN) return;
    float edv = ed[v];
    float eself = lrelu(es[v] + edv, 0.2f);
    float m = eself;
    int s = rp[v], e = rp[v + 1];
    int i = s;
    float lg[32];
    for (; i + 4 <= e; i += 4) {
        int u0 = col[i], u1 = col[i + 1], u2 = col[i + 2], u3 = col[i + 3];
        float t0 = lrelu(es[u0] + edv, 0.2f);
        float t1 = lrelu(es[u1] + edv, 0.2f);
        float t2 = lrelu(es[u2] + edv, 0.2f);
        float t3 = lrelu(es[u3] + edv, 0.2f);
        int k = i - s;
        if (k + 3 < 32) { lg[k] = t0; lg[k + 1] = t1; lg[k + 2] = t2; lg[k + 3] = t3; }
        m = fmaxf(m, fmaxf(fmaxf(t0, t1), fmaxf(t2, t3)));
    }
    for (; i < e; i++) {
        float t = lrelu(es[col[i]] + edv, 0.2f);
        int k = i - s;
        if (k < 32) lg[k] = t;
        m = fmaxf(m, t);
    }
    float wsl = __expf(eself - m);
    float den = wsl;
    for (i = s; i < e; i++) {
        int k = i - s;
        float t = (k < 32) ? lg[k] : lrelu(es[col[i]] + edv, 0.2f);
        float w = __expf(t - m);
        ew[i] = (f16)w;
        den += w;
    }
    wself[v] = wsl;
    invden[v] = 1.f / den;
}

// ---------------- GAT aggregation over fp16 rows (full-row, round-6 proven design) ----------------
__global__ __launch_bounds__(256) void gat_agg_h_k(const f16* __restrict__ y, const int* __restrict__ rp,
                                                   const int* __restrict__ col, const f16* __restrict__ ew,
                                                   const float* __restrict__ wself, const float* __restrict__ invden,
                                                   const float* __restrict__ bias, float* __restrict__ out) {
    int gid = blockIdx.x * 256 + threadIdx.x;
    int v = gid >> 4;
    int idx = gid & 15;
    const f16x4* y4 = (const f16x4*)y;
    float ws = wself[v];
    f16x4 self = y4[(size_t)v * 16 + idx];
    float accx = ws * (float)self.x, accy = ws * (float)self.y, accz = ws * (float)self.z, accw = ws * (float)self.w;
    int s = rp[v], e = rp[v + 1];
    int i = s;
    for (; i + 4 <= e; i += 4) {
        int u0 = col[i], u1 = col[i + 1], u2 = col[i + 2], u3 = col[i + 3];
        float w0 = (float)ew[i], w1 = (float)ew[i + 1], w2 = (float)ew[i + 2], w3 = (float)ew[i + 3];
        f16x4 a0 = y4[(size_t)u0 * 16 + idx];
        f16x4 a1 = y4[(size_t)u1 * 16 + idx];
        f16x4 a2 = y4[(size_t)u2 * 16 + idx];
        f16x4 a3 = y4[(size_t)u3 * 16 + idx];
        accx = fmaf(w0, (float)a0.x, fmaf(w1, (float)a1.x, fmaf(w2, (float)a2.x, fmaf(w3, (float)a3.x, accx))));
        accy = fmaf(w0, (float)a0.y, fmaf(w1, (float)a1.y, fmaf(w2, (float)a2.y, fmaf(w3, (float)a3.y, accy))));
        accz = fmaf(w0, (float)a0.z, fmaf(w1, (float)a1.z, fmaf(w2, (float)a2.z, fmaf(w3, (float)a3.z, accz))));
        accw = fmaf(w0, (float)a0.w, fmaf(w1, (float)a1.w, fmaf(w2, (float)a2.w, fmaf(w3, (float)a3.w, accw))));
    }
    for (; i < e; i++) {
        float w = (float)ew[i];
        f16x4 a = y4[(size_t)col[i] * 16 + idx];
        accx = fmaf(w, (float)a.x, accx); accy = fmaf(w, (float)a.y, accy);
        accz = fmaf(w, (float)a.z, accz); accw = fmaf(w, (float)a.w, accw);
    }
    float inv = invden[v];
    const float4* b4 = (const float4*)bias;
    float4 bb = b4[idx];
    float4 r;
    r.x = accx * inv + bb.x; r.y = accy * inv + bb.y;
    r.z = accz * inv + bb.z; r.w = accw * inv + bb.w;
    ((float4*)out)[(size_t)v * 16 + idx] = r;
}

// ---------------- pooling ----------------
__global__ void pool_pieces_k(const float* __restrict__ in, float* __restrict__ out) {
    int gid = blockIdx.x * 256 + threadIdx.x;
    if (gid >= BB * CCROSS * 64) return;
    int f = gid & 63, g = gid >> 6;
    const float* p = in + (size_t)g * PCC * 64 + f;
    float s = 0.f;
#pragma unroll 8
    for (int i = 0; i < PCC; i++) s += p[(size_t)i * 64];
    out[gid] = s * (1.f / 128.f);
}

__global__ void pool_cross_k(const float* __restrict__ in, float* __restrict__ out) {
    int gid = blockIdx.x * 64 + threadIdx.x;
    if (gid >= BB * 64) return;
    int f = gid & 63, b = gid >> 6;
    const float* p = in + (size_t)b * CCROSS * 64 + f;
    float s = 0.f;
#pragma unroll
    for (int i = 0; i < CCROSS; i++) s += p[(size_t)i * 64];
    out[gid] = s * (1.f / 32.f);
}

// ---------------- GAT input gemm (fp32, small cross-graph path) ----------------
template <int KIN, int KOUT>
__global__ void gat_gemm_k(const float* __restrict__ x, const float* __restrict__ W,
                           float* __restrict__ y, const float* __restrict__ av, const float* __restrict__ ad,
                           float* __restrict__ es, float* __restrict__ ed, int n) {
    int v = blockIdx.x * 256 + threadIdx.x;
    if (v >= n) return;
    const float* xr = x + (size_t)v * KIN;
    float acc[KOUT];
#pragma unroll
    for (int j = 0; j < KOUT; j++) acc[j] = 0.f;
#pragma unroll 2
    for (int k = 0; k < KIN; k++) {
        float xv = xr[k];
#pragma unroll
        for (int j = 0; j < KOUT; j++) acc[j] = fmaf(xv, W[k * KOUT + j], acc[j]);
    }
    float e1 = 0.f, e2 = 0.f;
    float4* y4 = (float4*)(y + (size_t)v * KOUT);
#pragma unroll
    for (int j4 = 0; j4 < KOUT / 4; j4++) {
        float4 t;
        t.x = acc[4 * j4 + 0]; t.y = acc[4 * j4 + 1]; t.z = acc[4 * j4 + 2]; t.w = acc[4 * j4 + 3];
        y4[j4] = t;
        e1 = fmaf(t.x, av[4 * j4 + 0], e1); e1 = fmaf(t.y, av[4 * j4 + 1], e1);
        e1 = fmaf(t.z, av[4 * j4 + 2], e1); e1 = fmaf(t.w, av[4 * j4 + 3], e1);
        e2 = fmaf(t.x, ad[4 * j4 + 0], e2); e2 = fmaf(t.y, ad[4 * j4 + 1], e2);
        e2 = fmaf(t.z, ad[4 * j4 + 2], e2); e2 = fmaf(t.w, ad[4 * j4 + 3], e2);
    }
    es[v] = e1; ed[v] = e2;
}

// ---------------- dense cross-graph GAT ----------------
__global__ void cross_att_k(const float* __restrict__ xw, const float* __restrict__ es,
                            const float* __restrict__ ed, const float* __restrict__ bg,
                            float* __restrict__ out) {
    int gid = blockIdx.x * 256 + threadIdx.x;
    if (gid >= BB * CCROSS * 64) return;
    int f = gid & 63;
    int d = (gid >> 6) & 31;
    int g = gid >> 11;
    int base = g * CCROSS;
    float edd = ed[base + d];
    float m = -1e30f;
#pragma unroll
    for (int s = 0; s < CCROSS; s++) {
        float e = lrelu(es[base + s] + edd, 0.2f);
        m = fmaxf(m, e);
    }
    float den = 0.f, acc = 0.f;
#pragma unroll
    for (int s = 0; s < CCROSS; s++) {
        float e = lrelu(es[base + s] + edd, 0.2f);
        float w = __expf(e - m) * ((s == d) ? 1.f : 2.f);
        den += w;
        acc = fmaf(w, xw[(size_t)(base + s) * 64 + f], acc);
    }
    out[gid] = acc / den + bg[f];
}

// ---------------- fused conv branch ----------------
#define S0_STR 264
#define S1_STR 132
#define S2_STR 66
#define S0_OFF 0
#define S1_OFF (3 * S0_STR)
#define S2_OFF (S1_OFF + 32 * S1_STR)
#define SMEM_FLOATS (S2_OFF + 64 * S2_STR)

__global__ __launch_bounds__(256) void conv_fused_k(
        const float* __restrict__ pts, const float* __restrict__ c1W, const float* __restrict__ c1b,
        const float* __restrict__ g1, const float* __restrict__ be1,
        const float* __restrict__ c2W, const float* __restrict__ c2b,
        const float* __restrict__ g2, const float* __restrict__ be2,
        const float* __restrict__ c3W, const float* __restrict__ c3b,
        float* __restrict__ partials) {
    __shared__ float smem[SMEM_FLOATS];
    float* s0 = smem + S0_OFF;
    float* s1 = smem + S1_OFF;
    float* s2 = smem + S2_OFF;
    float* s3 = smem;

    const int b = blockIdx.x >> 3;
    const int q = blockIdx.x & 7;
    const int tid = threadIdx.x;
    const float bnscale = 0.99999500003749968f;

    const int lo0 = 256 * q - 7;
    for (int t = tid; t < 3 * 263; t += 256) {
        int c = t / 263, j = t - c * 263;
        int p = lo0 + j;
        s0[c * S0_STR + j] = (p >= 0 && p < PP) ? pts[((size_t)b * 3 + c) * PP + p] : 0.f;
    }
    __syncthreads();

    const int lo1 = 128 * q - 3;
    for (int t = tid; t < 32 * 131; t += 256) {
        int ch = t / 131, j = t - ch * 131;
        int p1 = lo1 + j;
        float v = 0.f;
        if (p1 >= 0 && p1 < 1024) {
            float acc = c1b[ch];
            const float* w = c1W + ch * 9;
            const float* x0 = s0 + 2 * j;
#pragma unroll
            for (int ci = 0; ci < 3; ci++) {
                acc = fmaf(x0[ci * S0_STR + 0], w[ci * 3 + 0], acc);
                acc = fmaf(x0[ci * S0_STR + 1], w[ci * 3 + 1], acc);
                acc = fmaf(x0[ci * S0_STR + 2], w[ci * 3 + 2], acc);
            }
            acc = lrelu(acc, 0.01f);
            v = fmaf(acc, g1[ch] * bnscale, be1[ch]);
        }
        s1[ch * S1_STR + j] = v;
    }
    __syncthreads();

    const int lo2 = 64 * q - 1;
    for (int t = tid; t < 64 * 65; t += 256) {
        int ch = t / 65, j = t - ch * 65;
        int p2 = lo2 + j;
        float v = 0.f;
        if (p2 >= 0 && p2 < 512) {
            float acc = c2b[ch];
            const float* w = c2W + ch * 96;
            const float* x1 = s1 + 2 * j;
#pragma unroll
            for (int ci = 0; ci < 32; ci++) {
                acc = fmaf(x1[ci * S1_STR + 0], w[ci * 3 + 0], acc);
                acc = fmaf(x1[ci * S1_STR + 1], w[ci * 3 + 1], acc);
                acc = fmaf(x1[ci * S1_STR + 2], w[ci * 3 + 2], acc);
            }
            acc = lrelu(acc, 0.01f);
            v = fmaf(acc, g2[ch] * bnscale, be2[ch]);
        }
        s2[ch * S2_STR + j] = v;
    }
    __syncthreads();

    for (int t = tid; t < 64 * 32; t += 256) {
        int o = t >> 5, j = t & 31;
        float acc = c3b[o];
        const float* w = c3W + o * 192;
        const float* x2 = s2 + 2 * j;
#pragma unroll 16
        for (int ci = 0; ci < 64; ci++) {
            acc = fmaf(x2[ci * S2_STR + 0], w[ci * 3 + 0], acc);
            acc = fmaf(x2[ci * S2_STR + 1], w[ci * 3 + 1], acc);
            acc = fmaf(x2[ci * S2_STR + 2], w[ci * 3 + 2], acc);
        }
        s3[t] = lrelu(acc, 0.01f);
    }
    __syncthreads();

    if (tid < 64) {
        float s = 0.f;
#pragma unroll
        for (int j = 0; j < 32; j++) s += s3[tid * 32 + j];
        partials[((size_t)b * 8 + q) * 64 + tid] = s;
    }
}

// ---------------- head ----------------
__global__ void head_k(const float* __restrict__ hG, const float* __restrict__ partials,
                       const float* __restrict__ Wl2, const float* __restrict__ bl2,
                       const float* __restrict__ Wl3, const float* __restrict__ bl3,
                       float* __restrict__ out) {
    int b = blockIdx.x;
    int f = threadIdx.x;  // 64
    __shared__ float sh[64];
    float p = 0.f;
#pragma unroll
    for (int q = 0; q < 8; q++) p += partials[((size_t)b * 8 + q) * 64 + f];
    float h = hG[b * 64 + f] + p * (1.f / 256.f);
    sh[f] = h;
    __syncthreads();
    float acc = bl2[f];
#pragma unroll
    for (int k = 0; k < 64; k++) acc = fmaf(sh[k], Wl2[k * 64 + f], acc);
    acc = lrelu(acc, 0.01f);
    float pr = acc * Wl3[f];
#pragma unroll
    for (int off = 32; off > 0; off >>= 1) pr += __shfl_down(pr, off, 64);
    if (f == 0) out[b] = 1.f / (1.f + __expf(-(pr + bl3[0])));
}

extern "C" void kernel_launch(void* const* d_in, const int* in_sizes, int n_in,
                              void* d_out, int out_size, void* d_ws, size_t ws_size,
                              hipStream_t stream) {
    const float* x = (const float*)d_in[0];
    const int* ei = (const int*)d_in[1];
    const float* points = (const float*)d_in[2];
    const float* W1 = (const float*)d_in[3];
    const float* b1 = (const float*)d_in[4];
    const float* W2 = (const float*)d_in[5];
    const float* b2 = (const float*)d_in[6];
    const float* W3 = (const float*)d_in[7];
    const float* b3 = (const float*)d_in[8];
    const float* Wg1 = (const float*)d_in[9];
    const float* asrc1 = (const float*)d_in[10];
    const float* adst1 = (const float*)d_in[11];
    const float* bg1 = (const float*)d_in[12];
    const float* Wg2 = (const float*)d_in[13];
    const float* asrc2 = (const float*)d_in[14];
    const float* adst2 = (const float*)d_in[15];
    const float* bg2 = (const float*)d_in[16];
    const float* c1W = (const float*)d_in[17];
    const float* c1b = (const float*)d_in[18];
    const float* g1 = (const float*)d_in[19];
    const float* be1 = (const float*)d_in[20];
    const float* c2W = (const float*)d_in[21];
    const float* c2b = (const float*)d_in[22];
    const float* g2 = (const float*)d_in[23];
    const float* be2 = (const float*)d_in[24];
    const float* c3W = (const float*)d_in[25];
    const float* c3b = (const float*)d_in[26];
    const float* Wl2 = (const float*)d_in[27];
    const float* bl2 = (const float*)d_in[28];
    const float* Wl3 = (const float*)d_in[29];
    const float* bl3 = (const float*)d_in[30];

    const int* src = ei;
    const int* dst = ei + EE;

    // ---- workspace carve-up ----
    char* w = (char*)d_ws;
    size_t off = 0;
    auto A = [&](size_t bytes) -> void* {
        void* p = w + off;
        off = (off + bytes + 255) & ~(size_t)255;
        return p;
    };
    int* colb = (int*)A((size_t)EE * 4);
    int* rp = (int*)A((size_t)(NN + 1) * 4);
    int* gcnt = (int*)A(NBUCK * 4);
    int* bbase = (int*)A(NBUCK * 4);
    float* dinv = (float*)A((size_t)NN * 4);
    float* bufA = (float*)A((size_t)NN * 64 * 4);
    f16* bufH1 = (f16*)A((size_t)NN * 64 * 2);
    f16* bufH2 = (f16*)A((size_t)NN * 64 * 2);
    f16* ew = (f16*)A((size_t)EE * 2);
    float* wself = (float*)A((size_t)NN * 4);
    float* invden = (float*)A((size_t)NN * 4);
    float* es = (float*)A((size_t)NN * 4);
    float* edv = (float*)A((size_t)NN * 4);
    float* pooled = (float*)A((size_t)BB * CCROSS * 64 * 4);
    float* xw2 = (float*)A((size_t)BB * CCROSS * 64 * 4);
    float* es2 = (float*)A((size_t)BB * CCROSS * 4);
    float* ed2 = (float*)A((size_t)BB * CCROSS * 4);
    float* crosso = (float*)A((size_t)BB * CCROSS * 64 * 4);
    float* hG = (float*)A((size_t)BB * 64 * 4);
    float* partials = (float*)A((size_t)BB * 8 * 64 * 4);

    unsigned* buckets = (unsigned*)bufA;   // aliases bufA; dead before bufA's first real use (gat output)

    // ---- CSR build (bucketed) ----
    hipMemsetAsync(gcnt, 0, NBUCK * 4, stream);
    bucket_a_k<<<EE / 8192, 256, 0, stream>>>(src, dst, buckets, gcnt);
    bucket_scan_k<<<1, 256, 0, stream>>>(gcnt, bbase, rp);
    bucket_b_k<<<NBUCK, 256, 0, stream>>>(buckets, gcnt, bbase, rp, dinv, colb);

    // ---- points branch ----
    conv_fused_k<<<BB * 8, 256, 0, stream>>>(points, c1W, c1b, g1, be1, c2W, c2b, g2, be2, c3W, c3b, partials);

    // ---- GCN 1/2/3 + GAT gemm (fused agg+gemm chain, fp16 gather arrays) ----
    zprep_k<<<NN / 256, 256, 0, stream>>>(x, dinv, bufH1);                               // H1 = z1 [NN x 32h]
    fused_agg_gemm_k<19, 32, 0><<<NN / 32, 256, 0, stream>>>(bufH1, rp, colb, W1, dinv, b1, bufH2);  // H2 = z2 [NN x 32h]
    fused_agg_gemm_k<32, 64, 1><<<NN / 32, 256, 0, stream>>>(bufH2, rp, colb, W2, dinv, b2, bufH1);  // H1 = z3 [NN x 64h]
    fused_agg_gemm_gat_k<<<NN / 16, 256, 0, stream>>>(bufH1, rp, colb, W3, dinv, b3, Wg1, asrc1, adst1,
                                                      bufH2, es, edv);                   // H2 = xw [NN x 64h], es/ed

    // ---- GAT 1 softmax + aggregation ----
    gat_w_k<<<NN / 256, 256, 0, stream>>>(es, edv, rp, colb, ew, wself, invden);
    gat_agg_h_k<<<(NN * 16) / 256, 256, 0, stream>>>(bufH2, rp, colb, ew, wself, invden, bg1, bufA);  // bufA = gat out

    // ---- pool pieces -> cross GAT -> pool cross ----
    pool_pieces_k<<<(BB * CCROSS * 64) / 256, 256, 0, stream>>>(bufA, pooled);
    gat_gemm_k<64, 64><<<(BB * CCROSS) / 256, 256, 0, stream>>>(pooled, Wg2, xw2, asrc2, adst2, es2, ed2, BB * CCROSS);
    cross_att_k<<<(BB * CCROSS * 64) / 256, 256, 0, stream>>>(xw2, es2, ed2, bg2, crosso);
    pool_cross_k<<<BB, 64, 0, stream>>>(crosso, hG);

    // ---- head ----
    head_k<<<BB, 64, 0, stream>>>(hG, partials, Wl2, bl2, Wl3, bl3, (float*)d_out);
}